// Round 1
// 303.223 us; speedup vs baseline: 1.0983x; 1.0983x over previous
//
#include <hip/hip_runtime.h>
#include <hip/hip_bf16.h>

// Problem constants (fixed by the reference)
#define BATCH  2
#define SEQ    2048
#define DMODEL 1024
#define NHEAD  16
#define DHEAD  64

typedef _Float16 f16x4 __attribute__((ext_vector_type(4)));
typedef _Float16 f16x8 __attribute__((ext_vector_type(8)));
typedef float    f32x4 __attribute__((ext_vector_type(4)));

union H16 { unsigned short u; _Float16 f; };
__device__ __forceinline__ _Float16 u2h(unsigned short u) { H16 c; c.u = u; return c.f; }
__device__ __forceinline__ unsigned short h2u(_Float16 f) { H16 c; c.f = f; return c.u; }

// async global->LDS, 16 B per lane; LDS dest = wave-uniform base + lane*16.
__device__ __forceinline__ void gll16(const void* g, void* l) {
    __builtin_amdgcn_global_load_lds(
        (const __attribute__((address_space(1))) void*)g,
        (__attribute__((address_space(3))) void*)l, 16, 0, 0);
}

// max over the 16 lanes of a DPP row (C-matrix row group), in-register.
__device__ __forceinline__ float dpp_max16(float x) {
    float t;
    t = __int_as_float(__builtin_amdgcn_update_dpp(0, __float_as_int(x), 0xB1, 0xF, 0xF, true));   // quad_perm xor1
    x = fmaxf(x, t);
    t = __int_as_float(__builtin_amdgcn_update_dpp(0, __float_as_int(x), 0x4E, 0xF, 0xF, true));   // quad_perm xor2
    x = fmaxf(x, t);
    t = __int_as_float(__builtin_amdgcn_update_dpp(0, __float_as_int(x), 0x124, 0xF, 0xF, true));  // row_ror:4
    x = fmaxf(x, t);
    t = __int_as_float(__builtin_amdgcn_update_dpp(0, __float_as_int(x), 0x128, 0xF, 0xF, true));  // row_ror:8
    x = fmaxf(x, t);
    return x;
}

// ---------------------------------------------------------------------------
// Weight pack: W[k][n] fp32 -> WT[n][k] f16 hi (and lo) planes, x32 scaled.
// Chunk c (8 halves) within each 64-B group stored at c ^ sw(n),
// sw(n) = (n&3)^((n>>2)&3) — matches the gemm's frag-read swizzle.
// ---------------------------------------------------------------------------
__device__ __forceinline__ void pack_body(const float* __restrict__ W,
                                          _Float16* __restrict__ Phi,
                                          _Float16* __restrict__ Plo)
{
    const int n0 = blockIdx.x * 64;
    const int k0 = blockIdx.y * 64;
    const int t  = threadIdx.x;
    const int nl = t & 63;
    const int kc = (t >> 6) * 16;
    const int n  = n0 + nl;
    const int sw = (n & 3) ^ ((n >> 2) & 3);

    _Float16 hi[16], lo[16];
#pragma unroll
    for (int i = 0; i < 16; i++) {
        float x = W[(size_t)(k0 + kc + i) * DMODEL + n] * 32.0f;
        _Float16 h = (_Float16)x;
        hi[i] = h;
        lo[i] = (_Float16)(x - (float)h);
    }
#pragma unroll
    for (int cc = 0; cc < 2; cc++) {
        const int kk = kc + cc * 8;
        const int g  = kk >> 5;
        const int c  = (kk >> 3) & 3;
        const size_t off = (size_t)n * DMODEL + k0 + g * 32 + ((c ^ sw) << 3);
        *(f16x8*)&Phi[off] = *(f16x8*)&hi[cc * 8];
        if (Plo) *(f16x8*)&Plo[off] = *(f16x8*)&lo[cc * 8];
    }
}

__global__ __launch_bounds__(256) void pack_qkv(const float* __restrict__ Wq,
                                                const float* __restrict__ Wk,
                                                const float* __restrict__ Wv,
                                                _Float16* qhiT, _Float16* qloT,
                                                _Float16* khiT, _Float16* kloT,
                                                _Float16* vhiT)
{
    const int z = blockIdx.z;
    pack_body(z == 0 ? Wq : z == 1 ? Wk : Wv,
              z == 0 ? qhiT : z == 1 ? khiT : vhiT,
              z == 0 ? qloT : z == 1 ? kloT : nullptr);
}

__global__ __launch_bounds__(256) void pack_one(const float* __restrict__ W,
                                                _Float16* Phi)
{
    pack_body(W, Phi, nullptr);
}

// ---------------------------------------------------------------------------
// m97-style MFMA GEMM: C[M,N] = A[M,K] @ B[K,N]; A fp32 (in-kernel hi/lo
// convert), B from pre-packed transposed hi/lo planes via global_load_lds.
// 128x128 tile, 4 waves x (64x64), BK=32. SPLIT=3: Markidis fp32-grade.
//
// R1 restructure: A is now DOUBLE-BUFFERED in LDS with the same chunk-XOR
// swizzled stride-32 layout as B (was single-buffered pad-40), so the K-loop
// needs only ONE barrier per K-step (was 2). Iteration i computes from buf
// while staging A(regs->LDS) and B(gll) into buf^1; the end-of-iteration
// barrier drains gll + makes ds_writes visible. buf^1 was last READ in
// iteration i-1, whose barrier all waves passed => no WAR hazard.
// ---------------------------------------------------------------------------
template <int SPLIT, typename CT>
__global__ __launch_bounds__(256) void gemm_mfma(const float* __restrict__ A0,
                                                 const float* __restrict__ A1,
                                                 const _Float16* __restrict__ Bh0,
                                                 const _Float16* __restrict__ Bl0,
                                                 const _Float16* __restrict__ Bh1,
                                                 const _Float16* __restrict__ Bl1,
                                                 CT* __restrict__ C0,
                                                 CT* __restrict__ C1,
                                                 _Float16* __restrict__ Kh,
                                                 _Float16* __restrict__ Kl,
                                                 int N, int K)
{
    constexpr int PB  = 128 * 32;                    // one plane-buffer (halves)
    constexpr int AHI = 0;                           // + buf*PB
    constexpr int ALO = 2 * PB;                      // (SPLIT==3 only)
    constexpr int BHI = (SPLIT == 3 ? 4 : 2) * PB;   // + buf*PB
    constexpr int BLO = BHI + 2 * PB;                // (SPLIT==3 only)
    constexpr int TOT = (SPLIT == 3 ? 8 : 4) * PB;   // 64 KB / 32 KB
    __shared__ __align__(16) _Float16 smem[TOT];

    const float*    A  = blockIdx.z ? A1 : A0;
    const _Float16* Bh = blockIdx.z ? Bh1 : Bh0;
    const _Float16* Bl = blockIdx.z ? Bl1 : Bl0;
    CT*             C  = blockIdx.z ? C1 : C0;

    const int m0 = blockIdx.x * 128;
    const int n0 = blockIdx.y * 128;
    const int t    = threadIdx.x;
    const int wave = t >> 6;
    const int lane = t & 63;
    const int quad = lane >> 4;
    const int col  = lane & 15;
    const int wm   = (wave & 1) * 64;
    const int wn   = (wave >> 1) * 64;

    const int ar  = t >> 1;
    const int akc = (t & 1) * 16;
    const int asw = (ar & 3) ^ ((ar >> 2) & 3);      // A chunk swizzle key
    const float* Ap = A + (size_t)(m0 + ar) * K + akc;

    const _Float16* BhSrc = Bh + (size_t)(n0 + wave * 32 + (lane >> 2)) * K + (lane & 3) * 8;
    const _Float16* BlSrc = (SPLIT == 3)
        ? Bl + (size_t)(n0 + wave * 32 + (lane >> 2)) * K + (lane & 3) * 8 : nullptr;

    const int qe8 = (quad ^ ((col & 3) ^ ((col >> 2) & 3))) * 8;

    f32x4 acc[4][4];
#pragma unroll
    for (int mt = 0; mt < 4; mt++)
#pragma unroll
        for (int nt = 0; nt < 4; nt++) acc[mt][nt] = (f32x4){0.f, 0.f, 0.f, 0.f};

    float av[16];
    auto loadA = [&](int k0) {
#pragma unroll
        for (int g = 0; g < 4; g++) {
            float4 x = *(const float4*)(Ap + k0 + g * 4);
            av[g * 4 + 0] = x.x; av[g * 4 + 1] = x.y;
            av[g * 4 + 2] = x.z; av[g * 4 + 3] = x.w;
        }
    };
    auto issueB = [&](int k0, int buf) {
        _Float16* d0 = &smem[BHI + buf * PB + wave * 1024];
        gll16(BhSrc + k0, d0);
        gll16(BhSrc + (size_t)16 * K + k0, d0 + 512);
        if constexpr (SPLIT == 3) {
            _Float16* d1 = &smem[BLO + buf * PB + wave * 1024];
            gll16(BlSrc + k0, d1);
            gll16(BlSrc + (size_t)16 * K + k0, d1 + 512);
        }
    };
    // convert + store A regs into LDS buffer sbuf, B-style swizzled layout:
    // row stride 32 halves, chunk c stored at slot c ^ asw(row).
    auto storeA = [&](int sbuf) {
#pragma unroll
        for (int g = 0; g < 2; g++) {
            f16x8 h, l;
#pragma unroll
            for (int j = 0; j < 8; j++) {
                float x = av[g * 8 + j];
                _Float16 hh = (_Float16)x;
                h[j] = hh;
                l[j] = (_Float16)(x - (float)hh);
            }
            const int off = ar * 32 + ((((akc >> 3) + g) ^ asw) << 3);
            *(f16x8*)&smem[AHI + sbuf * PB + off] = h;
            if constexpr (SPLIT == 3)
                *(f16x8*)&smem[ALO + sbuf * PB + off] = l;
        }
    };

    // prologue: stage tile 0 into buf 0
    loadA(0);
    issueB(0, 0);
    storeA(0);
    __syncthreads();

    int buf = 0;
    for (int k0 = 0; k0 < K; k0 += 32, buf ^= 1) {
        const bool pre = (k0 + 32 < K);
        if (pre) {
            loadA(k0 + 32);          // global fp32 -> regs (lands during MFMA)
            issueB(k0 + 32, buf ^ 1);
        }

        f16x8 ah[4], al[4], bh[4], bl[4];
#pragma unroll
        for (int mt = 0; mt < 4; mt++) {
            const int arow = (wm + mt * 16 + col) * 32 + qe8;
            ah[mt] = *(f16x8*)&smem[AHI + buf * PB + arow];
            if constexpr (SPLIT == 3)
                al[mt] = *(f16x8*)&smem[ALO + buf * PB + arow];
        }
#pragma unroll
        for (int nt = 0; nt < 4; nt++) {
            const int brow = (wn + nt * 16 + col) * 32 + qe8;
            bh[nt] = *(f16x8*)&smem[BHI + buf * PB + brow];
            if constexpr (SPLIT == 3)
                bl[nt] = *(f16x8*)&smem[BLO + buf * PB + brow];
        }
#pragma unroll
        for (int nt = 0; nt < 4; nt++)
#pragma unroll
            for (int mt = 0; mt < 4; mt++) {
                acc[mt][nt] = __builtin_amdgcn_mfma_f32_16x16x32_f16(ah[mt], bh[nt], acc[mt][nt], 0, 0, 0);
                if constexpr (SPLIT == 3) {
                    acc[mt][nt] = __builtin_amdgcn_mfma_f32_16x16x32_f16(ah[mt], bl[nt], acc[mt][nt], 0, 0, 0);
                    acc[mt][nt] = __builtin_amdgcn_mfma_f32_16x16x32_f16(al[mt], bh[nt], acc[mt][nt], 0, 0, 0);
                }
            }

        if (pre) storeA(buf ^ 1);    // conversion VALU after MFMA; ds_writes land pre-barrier
        __syncthreads();             // drains gll(buf^1) + A(buf^1) visible; buf reads done
    }

    const float inv = 1.0f / 32.0f;
#pragma unroll
    for (int mt = 0; mt < 4; mt++)
#pragma unroll
        for (int nt = 0; nt < 4; nt++)
#pragma unroll
            for (int r = 0; r < 4; r++) {
                float val = acc[mt][nt][r] * inv;
                size_t idx = (size_t)(m0 + wm + mt * 16 + quad * 4 + r) * N
                           + n0 + wn + nt * 16 + col;
                if constexpr (SPLIT == 3) {
                    _Float16 h = (_Float16)val;
                    if (blockIdx.z == 0) {
                        _Float16 l = (_Float16)(val - (float)h);
                        C[idx] = (unsigned)h2u(h) | ((unsigned)h2u(l) << 16);
                    } else {            // K path: separate hi/lo planes for attn gll
                        Kh[idx] = h;
                        Kl[idx] = (_Float16)(val - (float)h);
                    }
                } else if constexpr (__is_same(CT, _Float16)) {
                    C[idx] = (_Float16)val;
                } else {
                    C[idx] = val;
                }
            }
}

// ---------------------------------------------------------------------------
// MFMA flash attention (causal), XCD-pinned. K staged via global_load_lds from
// hi/lo planes (double-buffered, per-lane 3-bit chunk-XOR source swizzle so
// the unpadded stride-64 b128 frag reads spread across all banks). Softmax
// row-max via DPP (no LDS permutes). l via MFMA row-sum. Softmax on UNSCALED
// scores (reference quirk), /sqrt(64)=8 at the end.
// ---------------------------------------------------------------------------
#define AKH 0
#define AKL 8192
#define AVT 16384
#define AVT_SIZE (64 * 72 + 64)
#define AP  (AVT + AVT_SIZE)
#define AP_WAVE (16 * 72)
#define ATOT (AP + 4 * AP_WAVE)          // 25664 halves = 51.3 KB

__global__ __launch_bounds__(256) void attn_mfma(unsigned* __restrict__ qa,
                                                 const _Float16* __restrict__ khi,
                                                 const _Float16* __restrict__ klo,
                                                 const _Float16* __restrict__ vh)
{
    __shared__ __align__(16) _Float16 smem[ATOT];

    const int i  = blockIdx.x;
    const int j  = i >> 3;
    const int bh = (i & 7) + ((j & 3) << 3);   // pin (b,h) to XCD i&7
    const int qt = (SEQ / 64 - 1) - (j >> 2);
    const int b  = bh >> 4;
    const int h  = bh & 15;
    const int qb = qt * 64;

    const int t    = threadIdx.x;
    const int wave = t >> 6;
    const int lane = t & 63;
    const int quad = lane >> 4;
    const int col  = lane & 15;

    const size_t bbase = (size_t)b * SEQ * DMODEL + (size_t)h * DHEAD;
    const _Float16* vb_ptr = vh + bbase;

    // --- Q fragments (A-operand, hi/lo) from packed uint32 (once) ---
    const int qm = qb + wave * 16 + col;
    f16x8 qhi[2], qlo[2];
    {
        const unsigned* qp = qa + bbase + (size_t)qm * DMODEL + quad * 8;
#pragma unroll
        for (int kt = 0; kt < 2; kt++) {
            uint4 u0 = *(const uint4*)(qp + kt * 32);
            uint4 u1 = *(const uint4*)(qp + kt * 32 + 4);
            unsigned us[8] = {u0.x, u0.y, u0.z, u0.w, u1.x, u1.y, u1.z, u1.w};
#pragma unroll
            for (int jj = 0; jj < 8; jj++) {
                qhi[kt][jj] = u2h((unsigned short)(us[jj] & 0xffffu));
                qlo[kt][jj] = u2h((unsigned short)(us[jj] >> 16));
            }
        }
    }

    // --- K gll staging constants: 8 lanes/row, chunk slot c = lane&7 holds
    //     global chunk c ^ (rowLocal&7); rowLocal = wave*16 + i*8 + (lane>>3).
    const int rl0  = wave * 16 + (lane >> 3);
    const int kswz = (lane & 7) ^ ((lane >> 3) & 7);
    const size_t kbase = ((size_t)b * SEQ + rl0) * DMODEL + h * DHEAD + (kswz << 3);

    auto issueK = [&](int kb, int buf) {
        const _Float16* sh = khi + kbase + (size_t)kb * DMODEL;
        const _Float16* sl = klo + kbase + (size_t)kb * DMODEL;
        _Float16* dh = &smem[AKH + buf * 4096 + wave * 1024];
        _Float16* dl = &smem[AKL + buf * 4096 + wave * 1024];
        gll16(sh, dh);
        gll16(sh + (size_t)8 * DMODEL, dh + 512);
        gll16(sl, dl);
        gll16(sl + (size_t)8 * DMODEL, dl + 512);
    };

    // --- V staging (register prefetch + b16 transpose, as before) ---
    const int srow = t >> 2;
    const int sdg  = (t & 3) << 4;
    const int vswz = (t & 3) * 16;
    f16x8 pv[2];
    auto loadV = [&](int kb) {
        const _Float16* vp = vb_ptr + (size_t)(kb + srow) * DMODEL + sdg;
        pv[0] = *(const f16x8*)vp;
        pv[1] = *(const f16x8*)(vp + 8);
    };

    f16x8 kOnes;
#pragma unroll
    for (int jj = 0; jj < 8; jj++) kOnes[jj] = (_Float16)1.0f;

    float m_i[4];
    f32x4 l4 = (f32x4){0.f, 0.f, 0.f, 0.f};
    f32x4 o[4];
#pragma unroll
    for (int r = 0; r < 4; r++) m_i[r] = -1e30f;
#pragma unroll
    for (int dt = 0; dt < 4; dt++) o[dt] = (f32x4){0.f, 0.f, 0.f, 0.f};

    const int wq0 = qb + wave * 16;
    _Float16* Pw = &smem[AP + wave * AP_WAVE];
    const int cs = col & 7;                  // frag-read swizzle key

    loadV(0);
    issueK(0, 0);

    int buf = 0;
    for (int kb = 0; kb <= qb; kb += 64, buf ^= 1) {
        __syncthreads();                     // prev compute done (drains gll(kb))

#pragma unroll
        for (int jj = 0; jj < 8; jj++) {
            smem[AVT + (sdg + jj    ) * 72 + vswz + srow] = pv[0][jj];
            smem[AVT + (sdg + 8 + jj) * 72 + vswz + srow] = pv[1][jj];
        }
        __syncthreads();                     // staging visible

        if (kb + 64 <= qb) { issueK(kb + 64, buf ^ 1); loadV(kb + 64); }

        // ---- QK^T: 16q x 64keys, split-f16 (3 MFMAs) ----
        f32x4 acc[4];
#pragma unroll
        for (int ct = 0; ct < 4; ct++) acc[ct] = (f32x4){0.f, 0.f, 0.f, 0.f};
#pragma unroll
        for (int kt = 0; kt < 2; kt++) {
#pragma unroll
            for (int ct = 0; ct < 4; ct++) {
                const int off = (ct * 16 + col) * 64 + ((((kt << 2) | quad) ^ cs) << 3);
                f16x8 bhi = *(f16x8*)&smem[AKH + buf * 4096 + off];
                f16x8 blo = *(f16x8*)&smem[AKL + buf * 4096 + off];
                acc[ct] = __builtin_amdgcn_mfma_f32_16x16x32_f16(qhi[kt], bhi, acc[ct], 0, 0, 0);
                acc[ct] = __builtin_amdgcn_mfma_f32_16x16x32_f16(qhi[kt], blo, acc[ct], 0, 0, 0);
                acc[ct] = __builtin_amdgcn_mfma_f32_16x16x32_f16(qlo[kt], bhi, acc[ct], 0, 0, 0);
            }
        }

        // ---- online softmax (row max via DPP, no LDS permutes) ----
        const bool need_mask = (kb + 63 > wq0);
#pragma unroll
        for (int r = 0; r < 4; r++) {
            const int qrow = wq0 + quad * 4 + r;
            float s0 = acc[0][r], s1 = acc[1][r], s2 = acc[2][r], s3 = acc[3][r];
            if (need_mask) {
                s0 = (kb +  0 + col <= qrow) ? s0 : -1e30f;
                s1 = (kb + 16 + col <= qrow) ? s1 : -1e30f;
                s2 = (kb + 32 + col <= qrow) ? s2 : -1e30f;
                s3 = (kb + 48 + col <= qrow) ? s3 : -1e30f;
            }
            float rm = dpp_max16(fmaxf(fmaxf(s0, s1), fmaxf(s2, s3)));
            const float mnew  = fmaxf(m_i[r], rm);
            const float alpha = __expf(m_i[r] - mnew);
            const float p0 = __expf(s0 - mnew), p1 = __expf(s1 - mnew);
            const float p2 = __expf(s2 - mnew), p3 = __expf(s3 - mnew);
            m_i[r] = mnew;
            l4[r] *= alpha;
#pragma unroll
            for (int dt = 0; dt < 4; dt++) o[dt][r] *= alpha;
            const int prow = quad * 4 + r;
            Pw[prow * 72 + col     ] = (_Float16)p0;
            Pw[prow * 72 + col + 16] = (_Float16)p1;
            Pw[prow * 72 + col + 32] = (_Float16)p2;
            Pw[prow * 72 + col + 48] = (_Float16)p3;
        }

        // ---- PV: O += P @ V; l += P @ ones ----
#pragma unroll
        for (int kt = 0; kt < 2; kt++) {
            f16x8 a = *(f16x8*)&Pw[col * 72 + kt * 32 + quad * 8];
            l4 = __builtin_amdgcn_mfma_f32_16x16x32_f16(a, kOnes, l4, 0, 0, 0);
#pragma unroll
            for (int dt = 0; dt < 4; dt++) {
                f16x8 bv = *(f16x8*)&smem[AVT + (dt * 16 + col) * 72 + (dt & 3) * 16 + kt * 32 + quad * 8];
                o[dt] = __builtin_amdgcn_mfma_f32_16x16x32_f16(a, bv, o[dt], 0, 0, 0);
            }
        }
    }

    // ---- epilogue: /l, /8; write att (fp32 bits) over packed qh ----
#pragma unroll
    for (int r = 0; r < 4; r++) {
        const float inv = 1.0f / (l4[r] * 8.0f);
        const int q = wq0 + quad * 4 + r;
        unsigned* op = qa + bbase + (size_t)q * DMODEL;
#pragma unroll
        for (int dt = 0; dt < 4; dt++)
            op[dt * 16 + col] = __float_as_uint(o[dt][r] * inv);
    }
}

// ---------------------------------------------------------------------------
// Launch. Inputs: q, k, v, mask(ignored), Wq, Wk, Wv, Wo — all fp32.
// ws (32 MB): qh packed u32 [0,16); khi f16 [16,24); klo f16 [24,32).
// d_out (16 MB) rotating scratch: weight planes [0,10 MB); vh f16 [0,8) after
// QK; wohiT -> khi region (dead after attn); out overwrites d_out at the end.
// ---------------------------------------------------------------------------
extern "C" void kernel_launch(void* const* d_in, const int* in_sizes, int n_in,
                              void* d_out, int out_size, void* d_ws, size_t ws_size,
                              hipStream_t stream)
{
    const float* q  = (const float*)d_in[0];
    const float* k  = (const float*)d_in[1];
    const float* v  = (const float*)d_in[2];
    const float* Wq = (const float*)d_in[4];
    const float* Wk = (const float*)d_in[5];
    const float* Wv = (const float*)d_in[6];
    const float* Wo = (const float*)d_in[7];
    float* out = (float*)d_out;

    const int    M   = BATCH * SEQ;             // 4096
    const size_t npe = (size_t)M * DMODEL;      // 4,194,304
    const size_t PW  = (size_t)DMODEL * DMODEL; // 1M halves per plane

    unsigned* qh    = (unsigned*)d_ws;                  // ws[0,16 MB)
    _Float16* khi_p = (_Float16*)(qh + npe);            // ws[16,24 MB)
    _Float16* klo_p = khi_p + npe;                      // ws[24,32 MB)

    _Float16* dh    = (_Float16*)d_out;
    _Float16* qhiT  = dh;
    _Float16* qloT  = dh + PW;
    _Float16* khiT  = dh + 2 * PW;
    _Float16* kloT  = dh + 3 * PW;
    _Float16* vhiT  = dh + 4 * PW;
    _Float16* vh    = dh;                               // d_out[0,8 MB) after QK
    _Float16* wohiT = khi_p;                            // khi region after attn

    dim3 b256(256);
    dim3 pk(DMODEL / 64, DMODEL / 64, 3);
    dim3 pk1(DMODEL / 64, DMODEL / 64, 1);
    dim3 gqk(M / 128, DMODEL / 128, 2);
    dim3 g1(M / 128, DMODEL / 128, 1);
    dim3 agrid(1024);

    pack_qkv<<<pk, b256, 0, stream>>>(Wq, Wk, Wv, qhiT, qloT, khiT, kloT, vhiT);
    gemm_mfma<3, unsigned><<<gqk, b256, 0, stream>>>(q, k, qhiT, qloT, khiT, kloT,
                                                     qh, nullptr, khi_p, klo_p,
                                                     DMODEL, DMODEL);
    gemm_mfma<1, _Float16><<<g1, b256, 0, stream>>>(v, v, vhiT, nullptr, vhiT, nullptr,
                                                    vh, vh, nullptr, nullptr,
                                                    DMODEL, DMODEL);
    attn_mfma<<<agrid, b256, 0, stream>>>(qh, khi_p, klo_p, vh);
    pack_one<<<pk1, b256, 0, stream>>>(Wo, wohiT);
    gemm_mfma<1, float><<<g1, b256, 0, stream>>>((const float*)qh, (const float*)qh,
                                                 wohiT, nullptr, wohiT, nullptr,
                                                 out, out, nullptr, nullptr,
                                                 DMODEL, DMODEL);
}

// Round 6
// 293.211 us; speedup vs baseline: 1.1358x; 1.0341x over previous
//
#include <hip/hip_runtime.h>
#include <hip/hip_bf16.h>

// Problem constants (fixed by the reference)
#define BATCH  2
#define SEQ    2048
#define DMODEL 1024
#define NHEAD  16
#define DHEAD  64

typedef _Float16 f16x4 __attribute__((ext_vector_type(4)));
typedef _Float16 f16x8 __attribute__((ext_vector_type(8)));
typedef float    f32x4 __attribute__((ext_vector_type(4)));

union H16 { unsigned short u; _Float16 f; };
__device__ __forceinline__ _Float16 u2h(unsigned short u) { H16 c; c.u = u; return c.f; }
__device__ __forceinline__ unsigned short h2u(_Float16 f) { H16 c; c.f = f; return c.u; }

// async global->LDS, 16 B per lane; LDS dest = wave-uniform base + lane*16.
__device__ __forceinline__ void gll16(const void* g, void* l) {
    __builtin_amdgcn_global_load_lds(
        (const __attribute__((address_space(1))) void*)g,
        (__attribute__((address_space(3))) void*)l, 16, 0, 0);
}

// max over the 16 lanes of a DPP row (C-matrix row group), in-register.
__device__ __forceinline__ float dpp_max16(float x) {
    float t;
    t = __int_as_float(__builtin_amdgcn_update_dpp(0, __float_as_int(x), 0xB1, 0xF, 0xF, true));   // quad_perm xor1
    x = fmaxf(x, t);
    t = __int_as_float(__builtin_amdgcn_update_dpp(0, __float_as_int(x), 0x4E, 0xF, 0xF, true));   // quad_perm xor2
    x = fmaxf(x, t);
    t = __int_as_float(__builtin_amdgcn_update_dpp(0, __float_as_int(x), 0x124, 0xF, 0xF, true));  // row_ror:4
    x = fmaxf(x, t);
    t = __int_as_float(__builtin_amdgcn_update_dpp(0, __float_as_int(x), 0x128, 0xF, 0xF, true));  // row_ror:8
    x = fmaxf(x, t);
    return x;
}

// ---------------------------------------------------------------------------
// Weight pack: W[k][n] fp32 -> WT[n][k] f16 hi (and lo) planes, x32 scaled.
// Chunk c (8 halves) within each 64-B group stored at c ^ sw(n),
// sw(n) = (n&3)^((n>>2)&3) — matches the gemm's frag-read swizzle.
// ---------------------------------------------------------------------------
__device__ __forceinline__ void pack_body(const float* __restrict__ W,
                                          _Float16* __restrict__ Phi,
                                          _Float16* __restrict__ Plo)
{
    const int n0 = blockIdx.x * 64;
    const int k0 = blockIdx.y * 64;
    const int t  = threadIdx.x;
    const int nl = t & 63;
    const int kc = (t >> 6) * 16;
    const int n  = n0 + nl;
    const int sw = (n & 3) ^ ((n >> 2) & 3);

    _Float16 hi[16], lo[16];
#pragma unroll
    for (int i = 0; i < 16; i++) {
        float x = W[(size_t)(k0 + kc + i) * DMODEL + n] * 32.0f;
        _Float16 h = (_Float16)x;
        hi[i] = h;
        lo[i] = (_Float16)(x - (float)h);
    }
#pragma unroll
    for (int cc = 0; cc < 2; cc++) {
        const int kk = kc + cc * 8;
        const int g  = kk >> 5;
        const int c  = (kk >> 3) & 3;
        const size_t off = (size_t)n * DMODEL + k0 + g * 32 + ((c ^ sw) << 3);
        *(f16x8*)&Phi[off] = *(f16x8*)&hi[cc * 8];
        if (Plo) *(f16x8*)&Plo[off] = *(f16x8*)&lo[cc * 8];
    }
}

__global__ __launch_bounds__(256) void pack_qkv(const float* __restrict__ Wq,
                                                const float* __restrict__ Wk,
                                                const float* __restrict__ Wv,
                                                _Float16* qhiT, _Float16* qloT,
                                                _Float16* khiT, _Float16* kloT,
                                                _Float16* vhiT)
{
    const int z = blockIdx.z;
    pack_body(z == 0 ? Wq : z == 1 ? Wk : Wv,
              z == 0 ? qhiT : z == 1 ? khiT : vhiT,
              z == 0 ? qloT : z == 1 ? kloT : nullptr);
}

__global__ __launch_bounds__(256) void pack_one(const float* __restrict__ W,
                                                _Float16* Phi)
{
    pack_body(W, Phi, nullptr);
}

// ---------------------------------------------------------------------------
// m97-style MFMA GEMM: C[M,N] = A[M,K] @ B[K,N]; A fp32 (in-kernel hi/lo
// convert), B from pre-packed transposed hi/lo planes via global_load_lds.
// A double-buffered in LDS, B-style chunk-XOR swizzled layout, single
// barrier per K-step (R1).
//
// R2: template param BM selects tile geometry.
//  BM=128: 128x128 tile, 4 waves x (64x64), grid M/128 x N/128.  (SPLIT=3 QK)
//  BM=64 :  64x128 tile, 4 waves x (64x32), grid M/64  x N/128.  (SPLIT=1)
// BM=64 exists because SPLIT=1 GEMMs previously launched 256 blocks on 256
// CUs = 1 wave/SIMD — zero TLP, every gll drain exposed. 512 blocks gives
// 2 blocks/CU so cross-block overlap hides the drains (same regime that
// makes the SPLIT=3 kernel efficient).
// ---------------------------------------------------------------------------
template <int SPLIT, int BM, typename CT>
__global__ __launch_bounds__(256) void gemm_mfma(const float* __restrict__ A0,
                                                 const float* __restrict__ A1,
                                                 const _Float16* __restrict__ Bh0,
                                                 const _Float16* __restrict__ Bl0,
                                                 const _Float16* __restrict__ Bh1,
                                                 const _Float16* __restrict__ Bl1,
                                                 CT* __restrict__ C0,
                                                 CT* __restrict__ C1,
                                                 _Float16* __restrict__ Kh,
                                                 _Float16* __restrict__ Kl,
                                                 int N, int K)
{
    constexpr int PBA = BM * 32;                      // A plane-buffer (halves)
    constexpr int PBB = 128 * 32;                     // B plane-buffer (halves)
    constexpr int AHI = 0;                            // + buf*PBA
    constexpr int ALO = 2 * PBA;                      // (SPLIT==3 only)
    constexpr int BHI = (SPLIT == 3 ? 4 : 2) * PBA;   // + buf*PBB
    constexpr int BLO = BHI + 2 * PBB;                // (SPLIT==3 only)
    constexpr int TOT = BHI + (SPLIT == 3 ? 4 : 2) * PBB;
    constexpr int NT  = (BM == 128) ? 4 : 2;
    __shared__ __align__(16) _Float16 smem[TOT];

    const float*    A  = blockIdx.z ? A1 : A0;
    const _Float16* Bh = blockIdx.z ? Bh1 : Bh0;
    const _Float16* Bl = blockIdx.z ? Bl1 : Bl0;
    CT*             C  = blockIdx.z ? C1 : C0;

    const int m0 = blockIdx.x * BM;
    const int n0 = blockIdx.y * 128;
    const int t    = threadIdx.x;
    const int wave = t >> 6;
    const int lane = t & 63;
    const int quad = lane >> 4;
    const int col  = lane & 15;
    const int wm   = (BM == 128) ? (wave & 1) * 64 : 0;
    const int wn   = (BM == 128) ? (wave >> 1) * 64 : wave * 32;

    // A staging assignment:
    //  BM=128: 2 threads/row, 16 floats each (4 float4 at akc..akc+16)
    //  BM=64 : 4 threads/row,  8 floats each (float4 at akc and akc+16)
    const int ar  = (BM == 128) ? (t >> 1) : (t >> 2);
    const int akc = (BM == 128) ? ((t & 1) * 16) : ((t & 3) * 4);
    const int asw = (ar & 3) ^ ((ar >> 2) & 3);      // A chunk swizzle key
    const float* Ap = A + (size_t)(m0 + ar) * K + akc;

    const _Float16* BhSrc = Bh + (size_t)(n0 + wave * 32 + (lane >> 2)) * K + (lane & 3) * 8;
    const _Float16* BlSrc = (SPLIT == 3)
        ? Bl + (size_t)(n0 + wave * 32 + (lane >> 2)) * K + (lane & 3) * 8 : nullptr;

    const int qe8 = (quad ^ ((col & 3) ^ ((col >> 2) & 3))) * 8;

    f32x4 acc[4][NT];
#pragma unroll
    for (int mt = 0; mt < 4; mt++)
#pragma unroll
        for (int nt = 0; nt < NT; nt++) acc[mt][nt] = (f32x4){0.f, 0.f, 0.f, 0.f};

    float av[(BM == 128) ? 16 : 8];
    auto loadA = [&](int k0) {
        if constexpr (BM == 128) {
#pragma unroll
            for (int g = 0; g < 4; g++) {
                float4 x = *(const float4*)(Ap + k0 + g * 4);
                av[g * 4 + 0] = x.x; av[g * 4 + 1] = x.y;
                av[g * 4 + 2] = x.z; av[g * 4 + 3] = x.w;
            }
        } else {
            float4 x = *(const float4*)(Ap + k0);
            float4 y = *(const float4*)(Ap + k0 + 16);
            av[0] = x.x; av[1] = x.y; av[2] = x.z; av[3] = x.w;
            av[4] = y.x; av[5] = y.y; av[6] = y.z; av[7] = y.w;
        }
    };
    auto issueB = [&](int k0, int buf) {
        _Float16* d0 = &smem[BHI + buf * PBB + wave * 1024];
        gll16(BhSrc + k0, d0);
        gll16(BhSrc + (size_t)16 * K + k0, d0 + 512);
        if constexpr (SPLIT == 3) {
            _Float16* d1 = &smem[BLO + buf * PBB + wave * 1024];
            gll16(BlSrc + k0, d1);
            gll16(BlSrc + (size_t)16 * K + k0, d1 + 512);
        }
    };
    // convert + store A regs into LDS buffer sbuf, B-style swizzled layout:
    // row stride 32 halves, chunk c stored at slot c ^ asw(row).
    auto storeA = [&](int sbuf) {
        if constexpr (BM == 128) {
#pragma unroll
            for (int g = 0; g < 2; g++) {
                f16x8 h, l;
#pragma unroll
                for (int j = 0; j < 8; j++) {
                    float x = av[g * 8 + j];
                    _Float16 hh = (_Float16)x;
                    h[j] = hh;
                    l[j] = (_Float16)(x - (float)hh);
                }
                const int off = ar * 32 + ((((akc >> 3) + g) ^ asw) << 3);
                *(f16x8*)&smem[AHI + sbuf * PBA + off] = h;
                if constexpr (SPLIT == 3)
                    *(f16x8*)&smem[ALO + sbuf * PBA + off] = l;
            }
        } else {
#pragma unroll
            for (int g = 0; g < 2; g++) {
                f16x4 h, l;
#pragma unroll
                for (int j = 0; j < 4; j++) {
                    float x = av[g * 4 + j];
                    _Float16 hh = (_Float16)x;
                    h[j] = hh;
                    l[j] = (_Float16)(x - (float)hh);
                }
                const int c   = ((akc + g * 16) >> 3);
                const int off = ar * 32 + ((c ^ asw) << 3) + (akc & 4);
                *(f16x4*)&smem[AHI + sbuf * PBA + off] = h;
                if constexpr (SPLIT == 3)
                    *(f16x4*)&smem[ALO + sbuf * PBA + off] = l;
            }
        }
    };

    // prologue: stage tile 0 into buf 0
    loadA(0);
    issueB(0, 0);
    storeA(0);
    __syncthreads();

    int buf = 0;
    for (int k0 = 0; k0 < K; k0 += 32, buf ^= 1) {
        const bool pre = (k0 + 32 < K);
        if (pre) {
            loadA(k0 + 32);          // global fp32 -> regs (lands during MFMA)
            issueB(k0 + 32, buf ^ 1);
        }

        f16x8 ah[4], al[4], bh[NT], bl[NT];
#pragma unroll
        for (int mt = 0; mt < 4; mt++) {
            const int arow = (wm + mt * 16 + col) * 32 + qe8;
            ah[mt] = *(f16x8*)&smem[AHI + buf * PBA + arow];
            if constexpr (SPLIT == 3)
                al[mt] = *(f16x8*)&smem[ALO + buf * PBA + arow];
        }
#pragma unroll
        for (int nt = 0; nt < NT; nt++) {
            const int brow = (wn + nt * 16 + col) * 32 + qe8;
            bh[nt] = *(f16x8*)&smem[BHI + buf * PBB + brow];
            if constexpr (SPLIT == 3)
                bl[nt] = *(f16x8*)&smem[BLO + buf * PBB + brow];
        }
#pragma unroll
        for (int nt = 0; nt < NT; nt++)
#pragma unroll
            for (int mt = 0; mt < 4; mt++) {
                acc[mt][nt] = __builtin_amdgcn_mfma_f32_16x16x32_f16(ah[mt], bh[nt], acc[mt][nt], 0, 0, 0);
                if constexpr (SPLIT == 3) {
                    acc[mt][nt] = __builtin_amdgcn_mfma_f32_16x16x32_f16(ah[mt], bl[nt], acc[mt][nt], 0, 0, 0);
                    acc[mt][nt] = __builtin_amdgcn_mfma_f32_16x16x32_f16(al[mt], bh[nt], acc[mt][nt], 0, 0, 0);
                }
            }

        if (pre) storeA(buf ^ 1);    // conversion VALU after MFMA; ds_writes land pre-barrier
        __syncthreads();             // drains gll(buf^1) + A(buf^1) visible; buf reads done
    }

    const float inv = 1.0f / 32.0f;
#pragma unroll
    for (int mt = 0; mt < 4; mt++)
#pragma unroll
        for (int nt = 0; nt < NT; nt++)
#pragma unroll
            for (int r = 0; r < 4; r++) {
                float val = acc[mt][nt][r] * inv;
                size_t idx = (size_t)(m0 + wm + mt * 16 + quad * 4 + r) * N
                           + n0 + wn + nt * 16 + col;
                if constexpr (SPLIT == 3) {
                    _Float16 h = (_Float16)val;
                    if (blockIdx.z == 0) {
                        _Float16 l = (_Float16)(val - (float)h);
                        C[idx] = (unsigned)h2u(h) | ((unsigned)h2u(l) << 16);
                    } else {            // K path: separate hi/lo planes for attn gll
                        Kh[idx] = h;
                        Kl[idx] = (_Float16)(val - (float)h);
                    }
                } else if constexpr (__is_same(CT, _Float16)) {
                    C[idx] = (_Float16)val;
                } else {
                    C[idx] = val;
                }
            }
}

// ---------------------------------------------------------------------------
// MFMA flash attention (causal), XCD-pinned. K staged via global_load_lds from
// hi/lo planes (double-buffered, per-lane 3-bit chunk-XOR source swizzle so
// the unpadded stride-64 b128 frag reads spread across all banks). Softmax
// row-max via DPP (no LDS permutes). l via MFMA row-sum. Softmax on UNSCALED
// scores (reference quirk), /sqrt(64)=8 at the end.
// ---------------------------------------------------------------------------
#define AKH 0
#define AKL 8192
#define AVT 16384
#define AVT_SIZE (64 * 72 + 64)
#define AP  (AVT + AVT_SIZE)
#define AP_WAVE (16 * 72)
#define ATOT (AP + 4 * AP_WAVE)          // 25664 halves = 51.3 KB

__global__ __launch_bounds__(256) void attn_mfma(unsigned* __restrict__ qa,
                                                 const _Float16* __restrict__ khi,
                                                 const _Float16* __restrict__ klo,
                                                 const _Float16* __restrict__ vh)
{
    __shared__ __align__(16) _Float16 smem[ATOT];

    const int i  = blockIdx.x;
    const int j  = i >> 3;
    const int bh = (i & 7) + ((j & 3) << 3);   // pin (b,h) to XCD i&7
    const int qt = (SEQ / 64 - 1) - (j >> 2);
    const int b  = bh >> 4;
    const int h  = bh & 15;
    const int qb = qt * 64;

    const int t    = threadIdx.x;
    const int wave = t >> 6;
    const int lane = t & 63;
    const int quad = lane >> 4;
    const int col  = lane & 15;

    const size_t bbase = (size_t)b * SEQ * DMODEL + (size_t)h * DHEAD;
    const _Float16* vb_ptr = vh + bbase;

    // --- Q fragments (A-operand, hi/lo) from packed uint32 (once) ---
    const int qm = qb + wave * 16 + col;
    f16x8 qhi[2], qlo[2];
    {
        const unsigned* qp = qa + bbase + (size_t)qm * DMODEL + quad * 8;
#pragma unroll
        for (int kt = 0; kt < 2; kt++) {
            uint4 u0 = *(const uint4*)(qp + kt * 32);
            uint4 u1 = *(const uint4*)(qp + kt * 32 + 4);
            unsigned us[8] = {u0.x, u0.y, u0.z, u0.w, u1.x, u1.y, u1.z, u1.w};
#pragma unroll
            for (int jj = 0; jj < 8; jj++) {
                qhi[kt][jj] = u2h((unsigned short)(us[jj] & 0xffffu));
                qlo[kt][jj] = u2h((unsigned short)(us[jj] >> 16));
            }
        }
    }

    // --- K gll staging constants: 8 lanes/row, chunk slot c = lane&7 holds
    //     global chunk c ^ (rowLocal&7); rowLocal = wave*16 + i*8 + (lane>>3).
    const int rl0  = wave * 16 + (lane >> 3);
    const int kswz = (lane & 7) ^ ((lane >> 3) & 7);
    const size_t kbase = ((size_t)b * SEQ + rl0) * DMODEL + h * DHEAD + (kswz << 3);

    auto issueK = [&](int kb, int buf) {
        const _Float16* sh = khi + kbase + (size_t)kb * DMODEL;
        const _Float16* sl = klo + kbase + (size_t)kb * DMODEL;
        _Float16* dh = &smem[AKH + buf * 4096 + wave * 1024];
        _Float16* dl = &smem[AKL + buf * 4096 + wave * 1024];
        gll16(sh, dh);
        gll16(sh + (size_t)8 * DMODEL, dh + 512);
        gll16(sl, dl);
        gll16(sl + (size_t)8 * DMODEL, dl + 512);
    };

    // --- V staging (register prefetch + b16 transpose, as before) ---
    const int srow = t >> 2;
    const int sdg  = (t & 3) << 4;
    const int vswz = (t & 3) * 16;
    f16x8 pv[2];
    auto loadV = [&](int kb) {
        const _Float16* vp = vb_ptr + (size_t)(kb + srow) * DMODEL + sdg;
        pv[0] = *(const f16x8*)vp;
        pv[1] = *(const f16x8*)(vp + 8);
    };

    f16x8 kOnes;
#pragma unroll
    for (int jj = 0; jj < 8; jj++) kOnes[jj] = (_Float16)1.0f;

    float m_i[4];
    f32x4 l4 = (f32x4){0.f, 0.f, 0.f, 0.f};
    f32x4 o[4];
#pragma unroll
    for (int r = 0; r < 4; r++) m_i[r] = -1e30f;
#pragma unroll
    for (int dt = 0; dt < 4; dt++) o[dt] = (f32x4){0.f, 0.f, 0.f, 0.f};

    const int wq0 = qb + wave * 16;
    _Float16* Pw = &smem[AP + wave * AP_WAVE];
    const int cs = col & 7;                  // frag-read swizzle key

    loadV(0);
    issueK(0, 0);

    int buf = 0;
    for (int kb = 0; kb <= qb; kb += 64, buf ^= 1) {
        __syncthreads();                     // prev compute done (drains gll(kb))

#pragma unroll
        for (int jj = 0; jj < 8; jj++) {
            smem[AVT + (sdg + jj    ) * 72 + vswz + srow] = pv[0][jj];
            smem[AVT + (sdg + 8 + jj) * 72 + vswz + srow] = pv[1][jj];
        }
        __syncthreads();                     // staging visible

        if (kb + 64 <= qb) { issueK(kb + 64, buf ^ 1); loadV(kb + 64); }

        // ---- QK^T: 16q x 64keys, split-f16 (3 MFMAs) ----
        f32x4 acc[4];
#pragma unroll
        for (int ct = 0; ct < 4; ct++) acc[ct] = (f32x4){0.f, 0.f, 0.f, 0.f};
#pragma unroll
        for (int kt = 0; kt < 2; kt++) {
#pragma unroll
            for (int ct = 0; ct < 4; ct++) {
                const int off = (ct * 16 + col) * 64 + ((((kt << 2) | quad) ^ cs) << 3);
                f16x8 bhi = *(f16x8*)&smem[AKH + buf * 4096 + off];
                f16x8 blo = *(f16x8*)&smem[AKL + buf * 4096 + off];
                acc[ct] = __builtin_amdgcn_mfma_f32_16x16x32_f16(qhi[kt], bhi, acc[ct], 0, 0, 0);
                acc[ct] = __builtin_amdgcn_mfma_f32_16x16x32_f16(qhi[kt], blo, acc[ct], 0, 0, 0);
                acc[ct] = __builtin_amdgcn_mfma_f32_16x16x32_f16(qlo[kt], bhi, acc[ct], 0, 0, 0);
            }
        }

        // ---- online softmax (row max via DPP, no LDS permutes) ----
        const bool need_mask = (kb + 63 > wq0);
#pragma unroll
        for (int r = 0; r < 4; r++) {
            const int qrow = wq0 + quad * 4 + r;
            float s0 = acc[0][r], s1 = acc[1][r], s2 = acc[2][r], s3 = acc[3][r];
            if (need_mask) {
                s0 = (kb +  0 + col <= qrow) ? s0 : -1e30f;
                s1 = (kb + 16 + col <= qrow) ? s1 : -1e30f;
                s2 = (kb + 32 + col <= qrow) ? s2 : -1e30f;
                s3 = (kb + 48 + col <= qrow) ? s3 : -1e30f;
            }
            float rm = dpp_max16(fmaxf(fmaxf(s0, s1), fmaxf(s2, s3)));
            const float mnew  = fmaxf(m_i[r], rm);
            const float alpha = __expf(m_i[r] - mnew);
            const float p0 = __expf(s0 - mnew), p1 = __expf(s1 - mnew);
            const float p2 = __expf(s2 - mnew), p3 = __expf(s3 - mnew);
            m_i[r] = mnew;
            l4[r] *= alpha;
#pragma unroll
            for (int dt = 0; dt < 4; dt++) o[dt][r] *= alpha;
            const int prow = quad * 4 + r;
            Pw[prow * 72 + col     ] = (_Float16)p0;
            Pw[prow * 72 + col + 16] = (_Float16)p1;
            Pw[prow * 72 + col + 32] = (_Float16)p2;
            Pw[prow * 72 + col + 48] = (_Float16)p3;
        }

        // ---- PV: O += P @ V; l += P @ ones ----
#pragma unroll
        for (int kt = 0; kt < 2; kt++) {
            f16x8 a = *(f16x8*)&Pw[col * 72 + kt * 32 + quad * 8];
            l4 = __builtin_amdgcn_mfma_f32_16x16x32_f16(a, kOnes, l4, 0, 0, 0);
#pragma unroll
            for (int dt = 0; dt < 4; dt++) {
                f16x8 bv = *(f16x8*)&smem[AVT + (dt * 16 + col) * 72 + (dt & 3) * 16 + kt * 32 + quad * 8];
                o[dt] = __builtin_amdgcn_mfma_f32_16x16x32_f16(a, bv, o[dt], 0, 0, 0);
            }
        }
    }

    // ---- epilogue: /l, /8; write att (fp32 bits) over packed qh ----
#pragma unroll
    for (int r = 0; r < 4; r++) {
        const float inv = 1.0f / (l4[r] * 8.0f);
        const int q = wq0 + quad * 4 + r;
        unsigned* op = qa + bbase + (size_t)q * DMODEL;
#pragma unroll
        for (int dt = 0; dt < 4; dt++)
            op[dt * 16 + col] = __float_as_uint(o[dt][r] * inv);
    }
}

// ---------------------------------------------------------------------------
// Launch. Inputs: q, k, v, mask(ignored), Wq, Wk, Wv, Wo — all fp32.
// ws (32 MB): qh packed u32 [0,16); khi f16 [16,24); klo f16 [24,32).
// d_out (16 MB) rotating scratch: weight planes [0,10 MB); vh f16 [0,8) after
// QK; wohiT -> khi region (dead after attn); out overwrites d_out at the end.
// ---------------------------------------------------------------------------
extern "C" void kernel_launch(void* const* d_in, const int* in_sizes, int n_in,
                              void* d_out, int out_size, void* d_ws, size_t ws_size,
                              hipStream_t stream)
{
    const float* q  = (const float*)d_in[0];
    const float* k  = (const float*)d_in[1];
    const float* v  = (const float*)d_in[2];
    const float* Wq = (const float*)d_in[4];
    const float* Wk = (const float*)d_in[5];
    const float* Wv = (const float*)d_in[6];
    const float* Wo = (const float*)d_in[7];
    float* out = (float*)d_out;

    const int    M   = BATCH * SEQ;             // 4096
    const size_t npe = (size_t)M * DMODEL;      // 4,194,304
    const size_t PW  = (size_t)DMODEL * DMODEL; // 1M halves per plane

    unsigned* qh    = (unsigned*)d_ws;                  // ws[0,16 MB)
    _Float16* khi_p = (_Float16*)(qh + npe);            // ws[16,24 MB)
    _Float16* klo_p = khi_p + npe;                      // ws[24,32 MB)

    _Float16* dh    = (_Float16*)d_out;
    _Float16* qhiT  = dh;
    _Float16* qloT  = dh + PW;
    _Float16* khiT  = dh + 2 * PW;
    _Float16* kloT  = dh + 3 * PW;
    _Float16* vhiT  = dh + 4 * PW;
    _Float16* vh    = dh;                               // d_out[0,8 MB) after QK
    _Float16* wohiT = khi_p;                            // khi region after attn

    dim3 b256(256);
    dim3 pk(DMODEL / 64, DMODEL / 64, 3);
    dim3 pk1(DMODEL / 64, DMODEL / 64, 1);
    dim3 gqk(M / 128, DMODEL / 128, 2);
    dim3 g64(M / 64, DMODEL / 128, 1);
    dim3 agrid(1024);

    pack_qkv<<<pk, b256, 0, stream>>>(Wq, Wk, Wv, qhiT, qloT, khiT, kloT, vhiT);
    gemm_mfma<3, 128, unsigned><<<gqk, b256, 0, stream>>>(q, k, qhiT, qloT, khiT, kloT,
                                                          qh, nullptr, khi_p, klo_p,
                                                          DMODEL, DMODEL);
    gemm_mfma<1, 64, _Float16><<<g64, b256, 0, stream>>>(v, v, vhiT, nullptr, vhiT, nullptr,
                                                         vh, vh, nullptr, nullptr,
                                                         DMODEL, DMODEL);
    attn_mfma<<<agrid, b256, 0, stream>>>(qh, khi_p, klo_p, vh);
    pack_one<<<pk1, b256, 0, stream>>>(Wo, wohiT);
    gemm_mfma<1, 64, float><<<g64, b256, 0, stream>>>((const float*)qh, (const float*)qh,
                                                      wohiT, nullptr, wohiT, nullptr,
                                                      out, out, nullptr, nullptr,
                                                      DMODEL, DMODEL);
}

// Round 7
// 281.931 us; speedup vs baseline: 1.1813x; 1.0400x over previous
//
#include <hip/hip_runtime.h>
#include <hip/hip_bf16.h>

// Problem constants (fixed by the reference)
#define BATCH  2
#define SEQ    2048
#define DMODEL 1024
#define NHEAD  16
#define DHEAD  64

typedef _Float16 f16x4 __attribute__((ext_vector_type(4)));
typedef _Float16 f16x8 __attribute__((ext_vector_type(8)));
typedef float    f32x4 __attribute__((ext_vector_type(4)));

union H16 { unsigned short u; _Float16 f; };
__device__ __forceinline__ _Float16 u2h(unsigned short u) { H16 c; c.u = u; return c.f; }
__device__ __forceinline__ unsigned short h2u(_Float16 f) { H16 c; c.f = f; return c.u; }

// async global->LDS, 16 B per lane; LDS dest = wave-uniform base + lane*16.
__device__ __forceinline__ void gll16(const void* g, void* l) {
    __builtin_amdgcn_global_load_lds(
        (const __attribute__((address_space(1))) void*)g,
        (__attribute__((address_space(3))) void*)l, 16, 0, 0);
}

// max over the 16 lanes of a DPP row (C-matrix row group), in-register.
__device__ __forceinline__ float dpp_max16(float x) {
    float t;
    t = __int_as_float(__builtin_amdgcn_update_dpp(0, __float_as_int(x), 0xB1, 0xF, 0xF, true));   // quad_perm xor1
    x = fmaxf(x, t);
    t = __int_as_float(__builtin_amdgcn_update_dpp(0, __float_as_int(x), 0x4E, 0xF, 0xF, true));   // quad_perm xor2
    x = fmaxf(x, t);
    t = __int_as_float(__builtin_amdgcn_update_dpp(0, __float_as_int(x), 0x124, 0xF, 0xF, true));  // row_ror:4
    x = fmaxf(x, t);
    t = __int_as_float(__builtin_amdgcn_update_dpp(0, __float_as_int(x), 0x128, 0xF, 0xF, true));  // row_ror:8
    x = fmaxf(x, t);
    return x;
}

// ---------------------------------------------------------------------------
// Weight pack: W[k][n] fp32 -> WT[n][k] f16 hi (and lo) planes, x32 scaled.
// Chunk c (8 halves) within each 64-B group stored at c ^ sw(n),
// sw(n) = (n&3)^((n>>2)&3) — matches the gemm's frag-read swizzle.
// ---------------------------------------------------------------------------
__device__ __forceinline__ void pack_body(const float* __restrict__ W,
                                          _Float16* __restrict__ Phi,
                                          _Float16* __restrict__ Plo)
{
    const int n0 = blockIdx.x * 64;
    const int k0 = blockIdx.y * 64;
    const int t  = threadIdx.x;
    const int nl = t & 63;
    const int kc = (t >> 6) * 16;
    const int n  = n0 + nl;
    const int sw = (n & 3) ^ ((n >> 2) & 3);

    _Float16 hi[16], lo[16];
#pragma unroll
    for (int i = 0; i < 16; i++) {
        float x = W[(size_t)(k0 + kc + i) * DMODEL + n] * 32.0f;
        _Float16 h = (_Float16)x;
        hi[i] = h;
        lo[i] = (_Float16)(x - (float)h);
    }
#pragma unroll
    for (int cc = 0; cc < 2; cc++) {
        const int kk = kc + cc * 8;
        const int g  = kk >> 5;
        const int c  = (kk >> 3) & 3;
        const size_t off = (size_t)n * DMODEL + k0 + g * 32 + ((c ^ sw) << 3);
        *(f16x8*)&Phi[off] = *(f16x8*)&hi[cc * 8];
        if (Plo) *(f16x8*)&Plo[off] = *(f16x8*)&lo[cc * 8];
    }
}

__global__ __launch_bounds__(256) void pack_qkv(const float* __restrict__ Wq,
                                                const float* __restrict__ Wk,
                                                const float* __restrict__ Wv,
                                                _Float16* qhiT, _Float16* qloT,
                                                _Float16* khiT, _Float16* kloT,
                                                _Float16* vhiT)
{
    const int z = blockIdx.z;
    pack_body(z == 0 ? Wq : z == 1 ? Wk : Wv,
              z == 0 ? qhiT : z == 1 ? khiT : vhiT,
              z == 0 ? qloT : z == 1 ? kloT : nullptr);
}

__global__ __launch_bounds__(256) void pack_one(const float* __restrict__ W,
                                                _Float16* Phi)
{
    pack_body(W, Phi, nullptr);
}

// ---------------------------------------------------------------------------
// m97-style MFMA GEMM: C[M,N] = A[M,K] @ B[K,N]; A fp32 (in-kernel hi/lo
// convert), B from pre-packed transposed hi/lo planes via global_load_lds.
// A double-buffered in LDS, B-style chunk-XOR swizzled layout, single
// barrier per iteration (R1).  BM selects tile geometry (R2).
//
// R6: template param U = K-steps per barrier (buffer ring = 2*U).
//  U=1: classic 2-buffer, 1 barrier per 32-K step.          (SPLIT=3 QK)
//  U=2: 4-buffer ring, iteration computes bufs {2p,2p+1} while staging
//       {2p^2, (2p^2)+1}; ONE barrier per 64 K.             (SPLIT=1)
// Rationale: SPLIT=1 steps have ~8 MFMA/wave — far too short to cover
// gll latency before the barrier's implicit vmcnt(0) drain, so每 step
// paid nearly full HBM/L2 latency (measured ~60 µs vs ~8 µs LDS floor).
// U=2 halves drain events AND doubles issue->drain compute distance.
// WAR safety: bufs staged at iter i were last READ at iter i-1, whose
// end-barrier all waves passed before any wave stages at iter i.
// ---------------------------------------------------------------------------
template <int SPLIT, int BM, int U, typename CT>
__global__ __launch_bounds__(256) void gemm_mfma(const float* __restrict__ A0,
                                                 const float* __restrict__ A1,
                                                 const _Float16* __restrict__ Bh0,
                                                 const _Float16* __restrict__ Bl0,
                                                 const _Float16* __restrict__ Bh1,
                                                 const _Float16* __restrict__ Bl1,
                                                 CT* __restrict__ C0,
                                                 CT* __restrict__ C1,
                                                 _Float16* __restrict__ Kh,
                                                 _Float16* __restrict__ Kl,
                                                 int N, int K)
{
    constexpr int PBA = BM * 32;                      // A plane-buffer (halves)
    constexpr int PBB = 128 * 32;                     // B plane-buffer (halves)
    constexpr int NB  = 2 * U;                        // buffers in the ring
    constexpr int AHI = 0;                            // + buf*PBA
    constexpr int ALO = NB * PBA;                     // (SPLIT==3 only)
    constexpr int BHI = (SPLIT == 3 ? 2 : 1) * NB * PBA;   // + buf*PBB
    constexpr int BLO = BHI + NB * PBB;               // (SPLIT==3 only)
    constexpr int TOT = BHI + (SPLIT == 3 ? 2 : 1) * NB * PBB;
    constexpr int NT  = (BM == 128) ? 4 : 2;
    __shared__ __align__(16) _Float16 smem[TOT];

    const float*    A  = blockIdx.z ? A1 : A0;
    const _Float16* Bh = blockIdx.z ? Bh1 : Bh0;
    const _Float16* Bl = blockIdx.z ? Bl1 : Bl0;
    CT*             C  = blockIdx.z ? C1 : C0;

    const int m0 = blockIdx.x * BM;
    const int n0 = blockIdx.y * 128;
    const int t    = threadIdx.x;
    const int wave = t >> 6;
    const int lane = t & 63;
    const int quad = lane >> 4;
    const int col  = lane & 15;
    const int wm   = (BM == 128) ? (wave & 1) * 64 : 0;
    const int wn   = (BM == 128) ? (wave >> 1) * 64 : wave * 32;

    // A staging assignment:
    //  BM=128: 2 threads/row, 16 floats each (4 float4)
    //  BM=64 : 4 threads/row,  8 floats per step (float4 at akc and akc+16)
    const int ar  = (BM == 128) ? (t >> 1) : (t >> 2);
    const int akc = (BM == 128) ? ((t & 1) * 16) : ((t & 3) * 4);
    const int asw = (ar & 3) ^ ((ar >> 2) & 3);      // A chunk swizzle key
    const float* Ap = A + (size_t)(m0 + ar) * K + akc;

    const _Float16* BhSrc = Bh + (size_t)(n0 + wave * 32 + (lane >> 2)) * K + (lane & 3) * 8;
    const _Float16* BlSrc = (SPLIT == 3)
        ? Bl + (size_t)(n0 + wave * 32 + (lane >> 2)) * K + (lane & 3) * 8 : nullptr;

    const int qe8 = (quad ^ ((col & 3) ^ ((col >> 2) & 3))) * 8;

    f32x4 acc[4][NT];
#pragma unroll
    for (int mt = 0; mt < 4; mt++)
#pragma unroll
        for (int nt = 0; nt < NT; nt++) acc[mt][nt] = (f32x4){0.f, 0.f, 0.f, 0.f};

    float av[16];                       // U=2/BM=64 uses halves [0,8),[8,16)
    auto loadA = [&](int k0, int sl) {
        if constexpr (BM == 128) {
#pragma unroll
            for (int g = 0; g < 4; g++) {
                float4 x = *(const float4*)(Ap + k0 + g * 4);
                av[g * 4 + 0] = x.x; av[g * 4 + 1] = x.y;
                av[g * 4 + 2] = x.z; av[g * 4 + 3] = x.w;
            }
        } else {
            float4 x = *(const float4*)(Ap + k0);
            float4 y = *(const float4*)(Ap + k0 + 16);
            av[sl * 8 + 0] = x.x; av[sl * 8 + 1] = x.y;
            av[sl * 8 + 2] = x.z; av[sl * 8 + 3] = x.w;
            av[sl * 8 + 4] = y.x; av[sl * 8 + 5] = y.y;
            av[sl * 8 + 6] = y.z; av[sl * 8 + 7] = y.w;
        }
    };
    auto issueB = [&](int k0, int buf) {
        _Float16* d0 = &smem[BHI + buf * PBB + wave * 1024];
        gll16(BhSrc + k0, d0);
        gll16(BhSrc + (size_t)16 * K + k0, d0 + 512);
        if constexpr (SPLIT == 3) {
            _Float16* d1 = &smem[BLO + buf * PBB + wave * 1024];
            gll16(BlSrc + k0, d1);
            gll16(BlSrc + (size_t)16 * K + k0, d1 + 512);
        }
    };
    // convert + store A regs into LDS buffer sbuf, B-style swizzled layout:
    // row stride 32 halves, chunk c stored at slot c ^ asw(row).
    auto storeA = [&](int sbuf, int sl) {
        if constexpr (BM == 128) {
#pragma unroll
            for (int g = 0; g < 2; g++) {
                f16x8 h, l;
#pragma unroll
                for (int j = 0; j < 8; j++) {
                    float x = av[g * 8 + j];
                    _Float16 hh = (_Float16)x;
                    h[j] = hh;
                    l[j] = (_Float16)(x - (float)hh);
                }
                const int off = ar * 32 + ((((akc >> 3) + g) ^ asw) << 3);
                *(f16x8*)&smem[AHI + sbuf * PBA + off] = h;
                if constexpr (SPLIT == 3)
                    *(f16x8*)&smem[ALO + sbuf * PBA + off] = l;
            }
        } else {
#pragma unroll
            for (int g = 0; g < 2; g++) {
                f16x4 h, l;
#pragma unroll
                for (int j = 0; j < 4; j++) {
                    float x = av[sl * 8 + g * 4 + j];
                    _Float16 hh = (_Float16)x;
                    h[j] = hh;
                    l[j] = (_Float16)(x - (float)hh);
                }
                const int c   = ((akc + g * 16) >> 3);
                const int off = ar * 32 + ((c ^ asw) << 3) + (akc & 4);
                *(f16x4*)&smem[AHI + sbuf * PBA + off] = h;
                if constexpr (SPLIT == 3)
                    *(f16x4*)&smem[ALO + sbuf * PBA + off] = l;
            }
        }
    };
    // frag reads + MFMA for one 32-K step from buffer `buf`
    auto computeStep = [&](int buf) {
        f16x8 ah[4], al[4], bh[NT], bl[NT];
#pragma unroll
        for (int mt = 0; mt < 4; mt++) {
            const int arow = (wm + mt * 16 + col) * 32 + qe8;
            ah[mt] = *(f16x8*)&smem[AHI + buf * PBA + arow];
            if constexpr (SPLIT == 3)
                al[mt] = *(f16x8*)&smem[ALO + buf * PBA + arow];
        }
#pragma unroll
        for (int nt = 0; nt < NT; nt++) {
            const int brow = (wn + nt * 16 + col) * 32 + qe8;
            bh[nt] = *(f16x8*)&smem[BHI + buf * PBB + brow];
            if constexpr (SPLIT == 3)
                bl[nt] = *(f16x8*)&smem[BLO + buf * PBB + brow];
        }
#pragma unroll
        for (int nt = 0; nt < NT; nt++)
#pragma unroll
            for (int mt = 0; mt < 4; mt++) {
                acc[mt][nt] = __builtin_amdgcn_mfma_f32_16x16x32_f16(ah[mt], bh[nt], acc[mt][nt], 0, 0, 0);
                if constexpr (SPLIT == 3) {
                    acc[mt][nt] = __builtin_amdgcn_mfma_f32_16x16x32_f16(ah[mt], bl[nt], acc[mt][nt], 0, 0, 0);
                    acc[mt][nt] = __builtin_amdgcn_mfma_f32_16x16x32_f16(al[mt], bh[nt], acc[mt][nt], 0, 0, 0);
                }
            }
    };

    // prologue: stage first U steps into bufs 0..U-1
    loadA(0, 0);
    issueB(0, 0);
    storeA(0, 0);
    if constexpr (U == 2) {
        loadA(32, 1);
        issueB(32, 1);
        storeA(1, 1);
    }
    __syncthreads();

    int ph = 0;
    for (int k0 = 0; k0 < K; k0 += 32 * U, ph ^= 1) {
        const int  cb  = ph * U;             // first compute buffer this iter
        const int  sb  = cb ^ U;             // first stage buffer this iter
        const bool pre = (k0 + 32 * U < K);
        if (pre) {
            loadA(k0 + 32 * U, 0);
            issueB(k0 + 32 * U, sb);
            if constexpr (U == 2) {
                loadA(k0 + 96, 1);
                issueB(k0 + 96, sb + 1);
            }
        }

        computeStep(cb);
        if constexpr (U == 2) computeStep(cb + 1);

        if (pre) {
            storeA(sb, 0);                   // conversion VALU after MFMA
            if constexpr (U == 2) storeA(sb + 1, 1);
        }
        __syncthreads();                     // drains glls; staged bufs visible
    }

    const float inv = 1.0f / 32.0f;
#pragma unroll
    for (int mt = 0; mt < 4; mt++)
#pragma unroll
        for (int nt = 0; nt < NT; nt++)
#pragma unroll
            for (int r = 0; r < 4; r++) {
                float val = acc[mt][nt][r] * inv;
                size_t idx = (size_t)(m0 + wm + mt * 16 + quad * 4 + r) * N
                           + n0 + wn + nt * 16 + col;
                if constexpr (SPLIT == 3) {
                    _Float16 h = (_Float16)val;
                    if (blockIdx.z == 0) {
                        _Float16 l = (_Float16)(val - (float)h);
                        C[idx] = (unsigned)h2u(h) | ((unsigned)h2u(l) << 16);
                    } else {            // K path: separate hi/lo planes for attn gll
                        Kh[idx] = h;
                        Kl[idx] = (_Float16)(val - (float)h);
                    }
                } else if constexpr (__is_same(CT, _Float16)) {
                    C[idx] = (_Float16)val;
                } else {
                    C[idx] = val;
                }
            }
}

// ---------------------------------------------------------------------------
// MFMA flash attention (causal), XCD-pinned. K staged via global_load_lds from
// hi/lo planes (double-buffered, per-lane 3-bit chunk-XOR source swizzle so
// the unpadded stride-64 b128 frag reads spread across all banks). Softmax
// row-max via DPP (no LDS permutes). l via MFMA row-sum. Softmax on UNSCALED
// scores (reference quirk), /sqrt(64)=8 at the end.
// ---------------------------------------------------------------------------
#define AKH 0
#define AKL 8192
#define AVT 16384
#define AVT_SIZE (64 * 72 + 64)
#define AP  (AVT + AVT_SIZE)
#define AP_WAVE (16 * 72)
#define ATOT (AP + 4 * AP_WAVE)          // 25664 halves = 51.3 KB

__global__ __launch_bounds__(256) void attn_mfma(unsigned* __restrict__ qa,
                                                 const _Float16* __restrict__ khi,
                                                 const _Float16* __restrict__ klo,
                                                 const _Float16* __restrict__ vh)
{
    __shared__ __align__(16) _Float16 smem[ATOT];

    const int i  = blockIdx.x;
    const int j  = i >> 3;
    const int bh = (i & 7) + ((j & 3) << 3);   // pin (b,h) to XCD i&7
    const int qt = (SEQ / 64 - 1) - (j >> 2);
    const int b  = bh >> 4;
    const int h  = bh & 15;
    const int qb = qt * 64;

    const int t    = threadIdx.x;
    const int wave = t >> 6;
    const int lane = t & 63;
    const int quad = lane >> 4;
    const int col  = lane & 15;

    const size_t bbase = (size_t)b * SEQ * DMODEL + (size_t)h * DHEAD;
    const _Float16* vb_ptr = vh + bbase;

    // --- Q fragments (A-operand, hi/lo) from packed uint32 (once) ---
    const int qm = qb + wave * 16 + col;
    f16x8 qhi[2], qlo[2];
    {
        const unsigned* qp = qa + bbase + (size_t)qm * DMODEL + quad * 8;
#pragma unroll
        for (int kt = 0; kt < 2; kt++) {
            uint4 u0 = *(const uint4*)(qp + kt * 32);
            uint4 u1 = *(const uint4*)(qp + kt * 32 + 4);
            unsigned us[8] = {u0.x, u0.y, u0.z, u0.w, u1.x, u1.y, u1.z, u1.w};
#pragma unroll
            for (int jj = 0; jj < 8; jj++) {
                qhi[kt][jj] = u2h((unsigned short)(us[jj] & 0xffffu));
                qlo[kt][jj] = u2h((unsigned short)(us[jj] >> 16));
            }
        }
    }

    // --- K gll staging constants: 8 lanes/row, chunk slot c = lane&7 holds
    //     global chunk c ^ (rowLocal&7); rowLocal = wave*16 + i*8 + (lane>>3).
    const int rl0  = wave * 16 + (lane >> 3);
    const int kswz = (lane & 7) ^ ((lane >> 3) & 7);
    const size_t kbase = ((size_t)b * SEQ + rl0) * DMODEL + h * DHEAD + (kswz << 3);

    auto issueK = [&](int kb, int buf) {
        const _Float16* sh = khi + kbase + (size_t)kb * DMODEL;
        const _Float16* sl = klo + kbase + (size_t)kb * DMODEL;
        _Float16* dh = &smem[AKH + buf * 4096 + wave * 1024];
        _Float16* dl = &smem[AKL + buf * 4096 + wave * 1024];
        gll16(sh, dh);
        gll16(sh + (size_t)8 * DMODEL, dh + 512);
        gll16(sl, dl);
        gll16(sl + (size_t)8 * DMODEL, dl + 512);
    };

    // --- V staging (register prefetch + b16 transpose, as before) ---
    const int srow = t >> 2;
    const int sdg  = (t & 3) << 4;
    const int vswz = (t & 3) * 16;
    f16x8 pv[2];
    auto loadV = [&](int kb) {
        const _Float16* vp = vb_ptr + (size_t)(kb + srow) * DMODEL + sdg;
        pv[0] = *(const f16x8*)vp;
        pv[1] = *(const f16x8*)(vp + 8);
    };

    f16x8 kOnes;
#pragma unroll
    for (int jj = 0; jj < 8; jj++) kOnes[jj] = (_Float16)1.0f;

    float m_i[4];
    f32x4 l4 = (f32x4){0.f, 0.f, 0.f, 0.f};
    f32x4 o[4];
#pragma unroll
    for (int r = 0; r < 4; r++) m_i[r] = -1e30f;
#pragma unroll
    for (int dt = 0; dt < 4; dt++) o[dt] = (f32x4){0.f, 0.f, 0.f, 0.f};

    const int wq0 = qb + wave * 16;
    _Float16* Pw = &smem[AP + wave * AP_WAVE];
    const int cs = col & 7;                  // frag-read swizzle key

    loadV(0);
    issueK(0, 0);

    int buf = 0;
    for (int kb = 0; kb <= qb; kb += 64, buf ^= 1) {
        __syncthreads();                     // prev compute done (drains gll(kb))

#pragma unroll
        for (int jj = 0; jj < 8; jj++) {
            smem[AVT + (sdg + jj    ) * 72 + vswz + srow] = pv[0][jj];
            smem[AVT + (sdg + 8 + jj) * 72 + vswz + srow] = pv[1][jj];
        }
        __syncthreads();                     // staging visible

        if (kb + 64 <= qb) { issueK(kb + 64, buf ^ 1); loadV(kb + 64); }

        // ---- QK^T: 16q x 64keys, split-f16 (3 MFMAs) ----
        f32x4 acc[4];
#pragma unroll
        for (int ct = 0; ct < 4; ct++) acc[ct] = (f32x4){0.f, 0.f, 0.f, 0.f};
#pragma unroll
        for (int kt = 0; kt < 2; kt++) {
#pragma unroll
            for (int ct = 0; ct < 4; ct++) {
                const int off = (ct * 16 + col) * 64 + ((((kt << 2) | quad) ^ cs) << 3);
                f16x8 bhi = *(f16x8*)&smem[AKH + buf * 4096 + off];
                f16x8 blo = *(f16x8*)&smem[AKL + buf * 4096 + off];
                acc[ct] = __builtin_amdgcn_mfma_f32_16x16x32_f16(qhi[kt], bhi, acc[ct], 0, 0, 0);
                acc[ct] = __builtin_amdgcn_mfma_f32_16x16x32_f16(qhi[kt], blo, acc[ct], 0, 0, 0);
                acc[ct] = __builtin_amdgcn_mfma_f32_16x16x32_f16(qlo[kt], bhi, acc[ct], 0, 0, 0);
            }
        }

        // ---- online softmax (row max via DPP, no LDS permutes) ----
        const bool need_mask = (kb + 63 > wq0);
#pragma unroll
        for (int r = 0; r < 4; r++) {
            const int qrow = wq0 + quad * 4 + r;
            float s0 = acc[0][r], s1 = acc[1][r], s2 = acc[2][r], s3 = acc[3][r];
            if (need_mask) {
                s0 = (kb +  0 + col <= qrow) ? s0 : -1e30f;
                s1 = (kb + 16 + col <= qrow) ? s1 : -1e30f;
                s2 = (kb + 32 + col <= qrow) ? s2 : -1e30f;
                s3 = (kb + 48 + col <= qrow) ? s3 : -1e30f;
            }
            float rm = dpp_max16(fmaxf(fmaxf(s0, s1), fmaxf(s2, s3)));
            const float mnew  = fmaxf(m_i[r], rm);
            const float alpha = __expf(m_i[r] - mnew);
            const float p0 = __expf(s0 - mnew), p1 = __expf(s1 - mnew);
            const float p2 = __expf(s2 - mnew), p3 = __expf(s3 - mnew);
            m_i[r] = mnew;
            l4[r] *= alpha;
#pragma unroll
            for (int dt = 0; dt < 4; dt++) o[dt][r] *= alpha;
            const int prow = quad * 4 + r;
            Pw[prow * 72 + col     ] = (_Float16)p0;
            Pw[prow * 72 + col + 16] = (_Float16)p1;
            Pw[prow * 72 + col + 32] = (_Float16)p2;
            Pw[prow * 72 + col + 48] = (_Float16)p3;
        }

        // ---- PV: O += P @ V; l += P @ ones ----
#pragma unroll
        for (int kt = 0; kt < 2; kt++) {
            f16x8 a = *(f16x8*)&Pw[col * 72 + kt * 32 + quad * 8];
            l4 = __builtin_amdgcn_mfma_f32_16x16x32_f16(a, kOnes, l4, 0, 0, 0);
#pragma unroll
            for (int dt = 0; dt < 4; dt++) {
                f16x8 bv = *(f16x8*)&smem[AVT + (dt * 16 + col) * 72 + (dt & 3) * 16 + kt * 32 + quad * 8];
                o[dt] = __builtin_amdgcn_mfma_f32_16x16x32_f16(a, bv, o[dt], 0, 0, 0);
            }
        }
    }

    // ---- epilogue: /l, /8; write att (fp32 bits) over packed qh ----
#pragma unroll
    for (int r = 0; r < 4; r++) {
        const float inv = 1.0f / (l4[r] * 8.0f);
        const int q = wq0 + quad * 4 + r;
        unsigned* op = qa + bbase + (size_t)q * DMODEL;
#pragma unroll
        for (int dt = 0; dt < 4; dt++)
            op[dt * 16 + col] = __float_as_uint(o[dt][r] * inv);
    }
}

// ---------------------------------------------------------------------------
// Launch. Inputs: q, k, v, mask(ignored), Wq, Wk, Wv, Wo — all fp32.
// ws (32 MB): qh packed u32 [0,16); khi f16 [16,24); klo f16 [24,32).
// d_out (16 MB) rotating scratch: weight planes [0,10 MB); vh f16 [0,8) after
// QK; wohiT -> khi region (dead after attn); out overwrites d_out at the end.
// ---------------------------------------------------------------------------
extern "C" void kernel_launch(void* const* d_in, const int* in_sizes, int n_in,
                              void* d_out, int out_size, void* d_ws, size_t ws_size,
                              hipStream_t stream)
{
    const float* q  = (const float*)d_in[0];
    const float* k  = (const float*)d_in[1];
    const float* v  = (const float*)d_in[2];
    const float* Wq = (const float*)d_in[4];
    const float* Wk = (const float*)d_in[5];
    const float* Wv = (const float*)d_in[6];
    const float* Wo = (const float*)d_in[7];
    float* out = (float*)d_out;

    const int    M   = BATCH * SEQ;             // 4096
    const size_t npe = (size_t)M * DMODEL;      // 4,194,304
    const size_t PW  = (size_t)DMODEL * DMODEL; // 1M halves per plane

    unsigned* qh    = (unsigned*)d_ws;                  // ws[0,16 MB)
    _Float16* khi_p = (_Float16*)(qh + npe);            // ws[16,24 MB)
    _Float16* klo_p = khi_p + npe;                      // ws[24,32 MB)

    _Float16* dh    = (_Float16*)d_out;
    _Float16* qhiT  = dh;
    _Float16* qloT  = dh + PW;
    _Float16* khiT  = dh + 2 * PW;
    _Float16* kloT  = dh + 3 * PW;
    _Float16* vhiT  = dh + 4 * PW;
    _Float16* vh    = dh;                               // d_out[0,8 MB) after QK
    _Float16* wohiT = khi_p;                            // khi region after attn

    dim3 b256(256);
    dim3 pk(DMODEL / 64, DMODEL / 64, 3);
    dim3 pk1(DMODEL / 64, DMODEL / 64, 1);
    dim3 gqk(M / 128, DMODEL / 128, 2);
    dim3 g64(M / 64, DMODEL / 128, 1);
    dim3 agrid(1024);

    pack_qkv<<<pk, b256, 0, stream>>>(Wq, Wk, Wv, qhiT, qloT, khiT, kloT, vhiT);
    gemm_mfma<3, 128, 1, unsigned><<<gqk, b256, 0, stream>>>(q, k, qhiT, qloT, khiT, kloT,
                                                             qh, nullptr, khi_p, klo_p,
                                                             DMODEL, DMODEL);
    gemm_mfma<1, 64, 2, _Float16><<<g64, b256, 0, stream>>>(v, v, vhiT, nullptr, vhiT, nullptr,
                                                            vh, vh, nullptr, nullptr,
                                                            DMODEL, DMODEL);
    attn_mfma<<<agrid, b256, 0, stream>>>(qh, khi_p, klo_p, vh);
    pack_one<<<pk1, b256, 0, stream>>>(Wo, wohiT);
    gemm_mfma<1, 64, 2, float><<<g64, b256, 0, stream>>>((const float*)qh, (const float*)qh,
                                                         wohiT, nullptr, wohiT, nullptr,
                                                         out, out, nullptr, nullptr,
                                                         DMODEL, DMODEL);
}